// Round 4
// baseline (497.461 us; speedup 1.0000x reference)
//
#include <hip/hip_runtime.h>
#include <math.h>

#define MM 16384
#define NN 8192
#define DD 128

#define L2E  1.4426950408889634f
#define COEF 0.15915494309189535f   // 1/(2*pi)

// ---------------------------------------------------------------------------
// bf16 helpers (RNE)
// ---------------------------------------------------------------------------
__device__ __forceinline__ unsigned short f2bf(float f) {
    unsigned u = __float_as_uint(f);
    u = (u + 0x7FFFu + ((u >> 16) & 1u)) >> 16;
    return (unsigned short)u;
}
__device__ __forceinline__ float bf2f(unsigned short h) {
    return __uint_as_float((unsigned)h << 16);
}

typedef __attribute__((ext_vector_type(8))) short bf16x8;
typedef __attribute__((ext_vector_type(4))) float f32x4;

// ---------------------------------------------------------------------------
// Pre-pass (B only): Bcat[n][0:128]=hi(mu), [128:256]=lo(mu - hi).
// mc[n] = (ln w_n - 0.5|mu_n|^2)*L2E.  16 lanes/row, 8 elems/lane.
// ---------------------------------------------------------------------------
__global__ __launch_bounds__(256) void gmm_prep_b(
    const float* __restrict__ means, const float* __restrict__ w,
    short* __restrict__ Bcat, float* __restrict__ mc)
{
    const int lane = threadIdx.x & 63;
    const int r    = lane >> 4;
    const int c    = lane & 15;
    const int n    = (blockIdx.x * 4 + (threadIdx.x >> 6)) * 4 + r;   // 0..8191

    const float* src = means + (size_t)n * DD + c * 8;
    float4 v0 = ((const float4*)src)[0];
    float4 v1 = ((const float4*)src)[1];
    float a[8] = {v0.x, v0.y, v0.z, v0.w, v1.x, v1.y, v1.z, v1.w};

    float ss = 0.f;
    #pragma unroll
    for (int k = 0; k < 8; ++k) ss = fmaf(a[k], a[k], ss);

    unsigned hi[4], lo[4];
    #pragma unroll
    for (int k = 0; k < 4; ++k) {
        unsigned short h0 = f2bf(a[2 * k]),     h1 = f2bf(a[2 * k + 1]);
        unsigned short l0 = f2bf(a[2 * k] - bf2f(h0));
        unsigned short l1 = f2bf(a[2 * k + 1] - bf2f(h1));
        hi[k] = (unsigned)h0 | ((unsigned)h1 << 16);
        lo[k] = (unsigned)l0 | ((unsigned)l1 << 16);
    }
    short* dst = Bcat + (size_t)n * 256 + c * 8;
    *(uint4*)(dst)       = make_uint4(hi[0], hi[1], hi[2], hi[3]);
    *(uint4*)(dst + 128) = make_uint4(lo[0], lo[1], lo[2], lo[3]);

    ss += __shfl_xor(ss, 1, 16);
    ss += __shfl_xor(ss, 2, 16);
    ss += __shfl_xor(ss, 4, 16);
    ss += __shfl_xor(ss, 8, 16);
    if (c == 0) mc[n] = (logf(w[n]) - 0.5f * ss) * L2E;
}

// ---------------------------------------------------------------------------
// Main kernel — barrier-free K-loop.
// Block: 64 rows x 2048-col strip (4 nt of 256 cols; 4 waves, wave-tile 64x64).
// A: x rows converted inline (hi/lo of x*L2E) into 32 KB LDS, layout
//    [g][row]: g=k-group (0..15 hi, 16..31 lo), 16 B per (g,row) -> b128 frag
//    reads are 256 B contiguous per 16-lane group (conflict-free).
// B: per-lane bf16x8 loads DIRECT from global (L2-resident; strip pinned to
//    an XCD via strip = bid&7). No LDS staging, no __syncthreads in K-loop ->
//    compiler pipelines loads across MFMAs with partial vmcnt (AITER pattern).
// K=384 as 12 ks-steps of 32: ks 0-3 a_hi*b_hi, 4-7 a_lo*b_hi, 8-11 a_hi*b_lo
// (A ks 8-11 re-reads LDS hi; B ks 4-7 re-reads global hi lines).
// Epilogue per nt: exp2(acc+xc+mc), width-16 shuffle, accumulate in LDS red.
// One partial store per block; reduce kernel finishes. No atomics, no spills
// (rowAcc lives in LDS; launch_bounds(256,3) -> 170-reg cap).
// ---------------------------------------------------------------------------
__global__ __launch_bounds__(256, 3) void gmm_mfma(
    const float* __restrict__ x, const short* __restrict__ Bcat,
    const float* __restrict__ mc, float* __restrict__ partials)
{
    __shared__ __align__(16) short As[16384];   // 32 KB: (g,row) at g*512+row*8
    __shared__ __align__(16) float xcs[64];
    __shared__ float red[4][64];

    const int tid  = threadIdx.x;
    const int w    = tid >> 6, lane = tid & 63;
    const int quad = lane >> 4, col = lane & 15;
    const int bid  = blockIdx.x;
    const int strip = bid & 7;                  // XCD-pinned strip (perf only)
    const int m0    = (bid >> 3) << 6;          // 64-row tile
    const int nb0   = strip << 10;              // 1024... strip covers 2048? see below

    // strips: 8 strips x 1024 cols? No: 4 nt * 256 = 1024 cols per block,
    // 8 strips * 1024 = 8192 ✓
    ((float*)red)[tid] = 0.f;

    // ---- inline A conversion: thread t -> row = t>>2, k-chunk (t&3)*32
    {
        const int row = tid >> 2;
        const int kq  = (tid & 3) * 32;
        const float* xr = x + (size_t)(m0 + row) * DD + kq;
        float ss = 0.f;
        #pragma unroll
        for (int g4 = 0; g4 < 4; ++g4) {
            float4 u0 = ((const float4*)xr)[g4 * 2];
            float4 u1 = ((const float4*)xr)[g4 * 2 + 1];
            float a[8] = {u0.x, u0.y, u0.z, u0.w, u1.x, u1.y, u1.z, u1.w};
            unsigned hi[4], lo[4];
            #pragma unroll
            for (int p = 0; p < 4; ++p) {
                ss = fmaf(a[2 * p], a[2 * p], fmaf(a[2 * p + 1], a[2 * p + 1], ss));
                float a0 = a[2 * p] * L2E, a1 = a[2 * p + 1] * L2E;
                unsigned short h0 = f2bf(a0), h1 = f2bf(a1);
                unsigned short l0 = f2bf(a0 - bf2f(h0)), l1 = f2bf(a1 - bf2f(h1));
                hi[p] = (unsigned)h0 | ((unsigned)h1 << 16);
                lo[p] = (unsigned)l0 | ((unsigned)l1 << 16);
            }
            const int g = (kq >> 3) + g4;               // 0..15
            *(uint4*)(As + g * 512 + row * 8)          = make_uint4(hi[0], hi[1], hi[2], hi[3]);
            *(uint4*)(As + (g + 16) * 512 + row * 8)   = make_uint4(lo[0], lo[1], lo[2], lo[3]);
        }
        // 4 threads per row are adjacent lanes -> xor-shuffle reduce
        ss += __shfl_xor(ss, 1, 64);
        ss += __shfl_xor(ss, 2, 64);
        if ((tid & 3) == 0) xcs[row] = -0.5f * ss * L2E;
    }
    __syncthreads();   // the ONLY barrier before the epilogue

    // A-frag LDS base: element (row=i*16+col, g=ksm*4+quad)
    const short* ap = As + quad * 512 + col * 8;

    // B pointers for nt=0 (row stride 256 shorts = 512 B)
    const short* bj[4];
    #pragma unroll
    for (int j = 0; j < 4; ++j)
        bj[j] = Bcat + (size_t)(nb0 + w * 64 + j * 16 + col) * 256 + quad * 8;

    bf16x8 bf[2][4];
    #pragma unroll
    for (int j = 0; j < 4; ++j) bf[0][j] = *(const bf16x8*)(bj[j]);   // ks=0

    #pragma unroll 1
    for (int nt = 0; nt < 4; ++nt) {
        f32x4 acc[4][4];
        #pragma unroll
        for (int i = 0; i < 4; ++i)
            #pragma unroll
            for (int j = 0; j < 4; ++j)
                acc[i][j] = (f32x4){0.f, 0.f, 0.f, 0.f};

        #pragma unroll
        for (int ks = 0; ks < 12; ++ks) {
            const int cur = ks & 1, nxt = cur ^ 1;
            if (ks < 11) {
                const int boff = ((ks + 1) < 4 ? (ks + 1) : (ks + 1) - 4) * 32;
                #pragma unroll
                for (int j = 0; j < 4; ++j)
                    bf[nxt][j] = *(const bf16x8*)(bj[j] + boff);
            } else if (nt != 3) {
                #pragma unroll
                for (int j = 0; j < 4; ++j) {
                    bj[j] += 256 * 256;                   // next 256-col group
                    bf[nxt][j] = *(const bf16x8*)(bj[j]); // ks=0 of next nt
                }
            }
            const int ksm = (ks < 8 ? ks : ks - 8);
            bf16x8 af[4];
            #pragma unroll
            for (int i = 0; i < 4; ++i)
                af[i] = *(const bf16x8*)(ap + ksm * 2048 + i * 128);
            #pragma unroll
            for (int j = 0; j < 4; ++j)
                #pragma unroll
                for (int i = 0; i < 4; ++i)
                    acc[i][j] = __builtin_amdgcn_mfma_f32_16x16x32_bf16(
                        af[i], bf[cur][j], acc[i][j], 0, 0, 0);
        }

        // epilogue for this nt (next nt's B loads already in flight)
        float mcv[4];
        #pragma unroll
        for (int j = 0; j < 4; ++j)
            mcv[j] = mc[nb0 + nt * 256 + w * 64 + j * 16 + col];

        #pragma unroll
        for (int i = 0; i < 4; ++i) {
            float4 xv = *(const float4*)&xcs[i * 16 + quad * 4];
            float xa[4] = {xv.x, xv.y, xv.z, xv.w};
            #pragma unroll
            for (int r = 0; r < 4; ++r) {
                float s = 0.f;
                #pragma unroll
                for (int j = 0; j < 4; ++j)
                    s += __builtin_exp2f(acc[i][j][r] + xa[r] + mcv[j]);
                s += __shfl_xor(s, 1, 16);
                s += __shfl_xor(s, 2, 16);
                s += __shfl_xor(s, 4, 16);
                s += __shfl_xor(s, 8, 16);
                if (col == 0) red[w][i * 16 + quad * 4 + r] += s;
            }
        }
    }

    __syncthreads();
    if (tid < 64)
        partials[(size_t)strip * MM + m0 + tid] =
            red[0][tid] + red[1][tid] + red[2][tid] + red[3][tid];
}

__global__ __launch_bounds__(256) void gmm_reduce(
    const float* __restrict__ partials, float* __restrict__ out)
{
    int m = blockIdx.x * 256 + threadIdx.x;
    float s = 0.f;
    #pragma unroll
    for (int k = 0; k < 8; ++k) s += partials[(size_t)k * MM + m];
    out[m] = COEF * s;
}

// ===========================================================================
// Fallback fp32 path (round-1) — only if ws_size is too small.
// ===========================================================================
__global__ __launch_bounds__(256) void gmm_prep(
    const float* __restrict__ x, const float* __restrict__ means,
    const float* __restrict__ w, float* __restrict__ xc, float* __restrict__ mc)
{
    int tid = blockIdx.x * 256 + threadIdx.x;
    if (tid < MM) {
        const float4* row = (const float4*)(x + (size_t)tid * DD);
        float ss = 0.f;
        #pragma unroll
        for (int i = 0; i < DD / 4; ++i) {
            float4 v = row[i];
            ss = fmaf(v.x, v.x, fmaf(v.y, v.y, fmaf(v.z, v.z, fmaf(v.w, v.w, ss))));
        }
        xc[tid] = -0.5f * ss * L2E;
    } else if (tid < MM + NN) {
        int n = tid - MM;
        const float4* row = (const float4*)(means + (size_t)n * DD);
        float ss = 0.f;
        #pragma unroll
        for (int i = 0; i < DD / 4; ++i) {
            float4 v = row[i];
            ss = fmaf(v.x, v.x, fmaf(v.y, v.y, fmaf(v.z, v.z, fmaf(v.w, v.w, ss))));
        }
        mc[n] = (logf(w[n]) - 0.5f * ss) * L2E;
    }
}

__global__ __launch_bounds__(256, 2) void gmm_main(
    const float* __restrict__ x, const float* __restrict__ means,
    const float* __restrict__ xc, const float* __restrict__ mc,
    float* __restrict__ out)
{
    __shared__ __align__(16) float Asm[128 * 128];
    __shared__ __align__(16) float Bsm[2][16 * 128];

    const int t   = threadIdx.x;
    const int tc  = t & 15;
    const int tr  = t >> 4;
    const int r0  = blockIdx.x * 128;
    const int nq0 = blockIdx.y * 2048;

    {
        float4 tmp[16];
        #pragma unroll
        for (int ii = 0; ii < 16; ++ii) {
            int idx = t + ii * 256;
            int r   = idx >> 5;
            int k0  = (idx & 31) << 2;
            tmp[ii] = *(const float4*)(x + (size_t)(r0 + r) * DD + k0);
        }
        #pragma unroll
        for (int ii = 0; ii < 16; ++ii) {
            int idx = t + ii * 256;
            int r   = idx >> 5;
            int k0  = (idx & 31) << 2;
            int rb  = r >> 3, rl = r & 7;
            float v[4] = {tmp[ii].x, tmp[ii].y, tmp[ii].z, tmp[ii].w};
            #pragma unroll
            for (int j = 0; j < 4; ++j) {
                int k = k0 + j;
                Asm[k * 128 + (((rb ^ (k & 15)) << 3) | rl)] = v[j];
            }
        }
    }

    float xcv[8];
    {
        float4 a = *(const float4*)(xc + r0 + tr * 8);
        float4 b = *(const float4*)(xc + r0 + tr * 8 + 4);
        xcv[0] = a.x; xcv[1] = a.y; xcv[2] = a.z; xcv[3] = a.w;
        xcv[4] = b.x; xcv[5] = b.y; xcv[6] = b.z; xcv[7] = b.w;
    }

    float rowAcc[8];
    #pragma unroll
    for (int i = 0; i < 8; ++i) rowAcc[i] = 0.f;

    for (int ntile = 0; ntile < 16; ++ntile) {
        const int nbase = nq0 + ntile * 128;

        float acc[8][8];
        #pragma unroll
        for (int i = 0; i < 8; ++i)
            #pragma unroll
            for (int j = 0; j < 8; ++j) acc[i][j] = 0.f;

        float4 ld[2];
        #pragma unroll
        for (int ii = 0; ii < 2; ++ii) {
            int flat = t + ii * 256;
            int nl   = flat >> 2;
            int kl   = (flat & 3) << 2;
            ld[ii] = *(const float4*)(means + (size_t)(nbase + nl) * DD + kl);
        }

        for (int ks = 0; ks < 8; ++ks) {
            const int buf = ks & 1;
            #pragma unroll
            for (int ii = 0; ii < 2; ++ii) {
                int flat = t + ii * 256;
                int nl   = flat >> 2;
                int k0   = (flat & 3) << 2;
                int nb   = nl >> 3, nll = nl & 7;
                float v[4] = {ld[ii].x, ld[ii].y, ld[ii].z, ld[ii].w};
                #pragma unroll
                for (int j = 0; j < 4; ++j) {
                    int kl = k0 + j;
                    Bsm[buf][kl * 128 + (((nb ^ kl) << 3) | nll)] = v[j];
                }
            }
            if (ks < 7) {
                #pragma unroll
                for (int ii = 0; ii < 2; ++ii) {
                    int flat = t + ii * 256;
                    int nl   = flat >> 2;
                    int kl   = (flat & 3) << 2;
                    ld[ii] = *(const float4*)(means + (size_t)(nbase + nl) * DD
                                              + (ks + 1) * 16 + kl);
                }
            }
            __syncthreads();

            #pragma unroll
            for (int kk = 0; kk < 16; ++kk) {
                const int k = ks * 16 + kk;
                const float* apx = &Asm[k * 128 + ((tr ^ kk) << 3)];
                float4 a0 = *(const float4*)apx;
                float4 a1 = *(const float4*)(apx + 4);
                const float* bpx = &Bsm[buf][kk * 128 + ((tc ^ kk) << 3)];
                float4 b0 = *(const float4*)bpx;
                float4 b1 = *(const float4*)(bpx + 4);
                float av[8] = {a0.x, a0.y, a0.z, a0.w, a1.x, a1.y, a1.z, a1.w};
                float bv[8] = {b0.x, b0.y, b0.z, b0.w, b1.x, b1.y, b1.z, b1.w};
                #pragma unroll
                for (int i = 0; i < 8; ++i)
                    #pragma unroll
                    for (int j = 0; j < 8; ++j)
                        acc[i][j] = fmaf(av[i], bv[j], acc[i][j]);
            }
        }

        float mcv[8];
        {
            float4 a = *(const float4*)(mc + nbase + tc * 8);
            float4 b = *(const float4*)(mc + nbase + tc * 8 + 4);
            mcv[0] = a.x; mcv[1] = a.y; mcv[2] = a.z; mcv[3] = a.w;
            mcv[4] = b.x; mcv[5] = b.y; mcv[6] = b.z; mcv[7] = b.w;
        }
        #pragma unroll
        for (int i = 0; i < 8; ++i) {
            float s = 0.f;
            #pragma unroll
            for (int j = 0; j < 8; ++j) {
                float arg = fmaf(acc[i][j], L2E, xcv[i] + mcv[j]);
                s += __builtin_exp2f(arg);
            }
            rowAcc[i] += s;
        }
    }

    #pragma unroll
    for (int i = 0; i < 8; ++i) {
        float v = rowAcc[i];
        v += __shfl_xor(v, 1, 16);
        v += __shfl_xor(v, 2, 16);
        v += __shfl_xor(v, 4, 16);
        v += __shfl_xor(v, 8, 16);
        if (tc == 0) atomicAdd(out + r0 + tr * 8 + i, COEF * v);
    }
}

extern "C" void kernel_launch(void* const* d_in, const int* in_sizes, int n_in,
                              void* d_out, int out_size, void* d_ws, size_t ws_size,
                              hipStream_t stream) {
    const float* x     = (const float*)d_in[0];
    const float* means = (const float*)d_in[1];
    const float* w     = (const float*)d_in[2];
    float* out = (float*)d_out;

    const size_t needB = (size_t)NN * 256 * sizeof(short);   // 4.2 MB
    const size_t need  = needB + (size_t)NN * 4 + (size_t)8 * MM * 4;

    if (ws_size >= need) {
        short* Bcat     = (short*)d_ws;
        float* mc       = (float*)(Bcat + (size_t)NN * 256);
        float* partials = mc + NN;
        gmm_prep_b<<<NN / 16, 256, 0, stream>>>(means, w, Bcat, mc);
        gmm_mfma<<<(MM / 64) * 8, 256, 0, stream>>>(x, Bcat, mc, partials);
        gmm_reduce<<<MM / 256, 256, 0, stream>>>(partials, out);
    } else {
        float* xc = (float*)d_ws;
        float* mc = xc + MM;
        hipMemsetAsync(out, 0, MM * sizeof(float), stream);
        gmm_prep<<<(MM + NN + 255) / 256, 256, 0, stream>>>(x, means, w, xc, mc);
        gmm_main<<<dim3(MM / 128, 4), 256, 0, stream>>>(x, means, xc, mc, out);
    }
}

// Round 5
// 213.289 us; speedup vs baseline: 2.3323x; 2.3323x over previous
//
#include <hip/hip_runtime.h>
#include <math.h>

#define MM 16384
#define NN 8192
#define DD 128

#define L2E  1.4426950408889634f
#define COEF 0.15915494309189535f   // 1/(2*pi)

// ---------------------------------------------------------------------------
// bf16 helpers (RNE)
// ---------------------------------------------------------------------------
__device__ __forceinline__ unsigned short f2bf(float f) {
    unsigned u = __float_as_uint(f);
    u = (u + 0x7FFFu + ((u >> 16) & 1u)) >> 16;
    return (unsigned short)u;
}
__device__ __forceinline__ float bf2f(unsigned short h) {
    return __uint_as_float((unsigned)h << 16);
}

__device__ __forceinline__ void async16(short* lds, const short* g) {
    __builtin_amdgcn_global_load_lds(
        (const __attribute__((address_space(1))) unsigned int*)g,
        (__attribute__((address_space(3))) unsigned int*)lds,
        16, 0, 0);
}

typedef __attribute__((ext_vector_type(8))) short bf16x8;
typedef __attribute__((ext_vector_type(4))) float f32x4;

// ---------------------------------------------------------------------------
// Pre-pass: 16 lanes per row (8 elems/lane).
//  x rows    -> Acat[m][0:128]=hi(x*L2E), [128:256]=lo, [256:384]=hi
//  mean rows -> Bcat[n][0:128]=hi(mu),    [128:256]=hi, [256:384]=lo
//  dot(Acat_row, Bcat_row) = a_hi*b_hi + a_lo*b_hi + a_hi*b_lo ~= (x*L2E).mu
//  xc[m] = -0.5|x|^2*L2E ; mc[n] = (ln w - 0.5|mu|^2)*L2E
// ---------------------------------------------------------------------------
__global__ __launch_bounds__(256) void gmm_prep_bf16(
    const float* __restrict__ x, const float* __restrict__ means,
    const float* __restrict__ w, short* __restrict__ Acat,
    short* __restrict__ Bcat, float* __restrict__ xc, float* __restrict__ mc)
{
    const int lane = threadIdx.x & 63;
    const int r    = lane >> 4;
    const int c    = lane & 15;
    const int row  = (blockIdx.x * 4 + (threadIdx.x >> 6)) * 4 + r;  // 0..24575
    const bool isx = row < MM;
    const int n    = row - MM;

    const float* src = isx ? (x + (size_t)row * DD + c * 8)
                           : (means + (size_t)n * DD + c * 8);
    float4 v0 = ((const float4*)src)[0];
    float4 v1 = ((const float4*)src)[1];
    float a[8] = {v0.x, v0.y, v0.z, v0.w, v1.x, v1.y, v1.z, v1.w};

    float ss = 0.f;
    #pragma unroll
    for (int k = 0; k < 8; ++k) ss = fmaf(a[k], a[k], ss);

    if (isx) {
        #pragma unroll
        for (int k = 0; k < 8; ++k) a[k] *= L2E;
    }

    unsigned hi[4], lo[4];
    #pragma unroll
    for (int k = 0; k < 4; ++k) {
        unsigned short h0 = f2bf(a[2 * k]),     h1 = f2bf(a[2 * k + 1]);
        unsigned short l0 = f2bf(a[2 * k] - bf2f(h0));
        unsigned short l1 = f2bf(a[2 * k + 1] - bf2f(h1));
        hi[k] = (unsigned)h0 | ((unsigned)h1 << 16);
        lo[k] = (unsigned)l0 | ((unsigned)l1 << 16);
    }
    uint4 HI = make_uint4(hi[0], hi[1], hi[2], hi[3]);
    uint4 LO = make_uint4(lo[0], lo[1], lo[2], lo[3]);

    short* dst = (isx ? Acat + (size_t)row * 384 : Bcat + (size_t)n * 384) + c * 8;
    *(uint4*)(dst)       = HI;
    *(uint4*)(dst + 128) = isx ? LO : HI;
    *(uint4*)(dst + 256) = isx ? HI : LO;

    ss += __shfl_xor(ss, 1, 16);
    ss += __shfl_xor(ss, 2, 16);
    ss += __shfl_xor(ss, 4, 16);
    ss += __shfl_xor(ss, 8, 16);
    if (c == 0) {
        if (isx) xc[row] = -0.5f * ss * L2E;
        else     mc[n]   = (logf(w[n]) - 0.5f * ss) * L2E;
    }
}

// ---------------------------------------------------------------------------
// Main MFMA kernel — round-2 structure + DOUBLE-BUFFERED staging with
// prefetch-issued-AFTER-the-barrier. One barrier per k-step; the staging
// batch a barrier waits on was issued one full compute phase earlier, so
// global->LDS latency is hidden (the round-2 version exposed it every step).
// 128x128 tile, 4 waves 2x2, BK=32, K=384 (12 steps).
// Epilogue: exp2(acc + xc + mc), width-16 shuffle reduce, partials store
// (no atomics); gmm_reduce sums the 64 column-strips.
// LDS: 2*16 KB staging + 1.5 KB -> 33.5 KB => 3 blocks/CU at (256,3).
// Register state identical to round 2 (76 VGPR, no spill).
// ---------------------------------------------------------------------------
__global__ __launch_bounds__(256, 3) void gmm_mfma(
    const short* __restrict__ Acat, const short* __restrict__ Bcat,
    const float* __restrict__ xc, const float* __restrict__ mc,
    float* __restrict__ partials)
{
    __shared__ __align__(16) short As[2][128 * 32];   // 2 x 8 KB
    __shared__ __align__(16) short Bs[2][128 * 32];   // 2 x 8 KB
    __shared__ __align__(16) float xcs[128];
    __shared__ float red[2][128];

    const int tid  = threadIdx.x;
    const int w    = tid >> 6, lane = tid & 63;
    const int wm   = w >> 1,   wn   = w & 1;
    const int quad = lane >> 4, col = lane & 15;
    const int m0   = blockIdx.x * 128;
    const int nb   = blockIdx.y * 128;

    const short* ga0 = Acat + (size_t)(m0 + w * 32 + (lane >> 2)) * 384 + (lane & 3) * 8;
    const short* ga1 = ga0 + (size_t)16 * 384;
    const short* gb0 = Bcat + (size_t)(nb + w * 32 + (lane >> 2)) * 384 + (lane & 3) * 8;
    const short* gb1 = gb0 + (size_t)16 * 384;
    const int lofs0 = (w * 32) * 32;
    const int lofs1 = (w * 32 + 16) * 32;

    if (tid < 128) xcs[tid] = xc[m0 + tid];

    // stage k-step 0 into buffer 0
    async16(&As[0][lofs0], ga0);
    async16(&As[0][lofs1], ga1);
    async16(&Bs[0][lofs0], gb0);
    async16(&Bs[0][lofs1], gb1);

    f32x4 acc[4][4];
    #pragma unroll
    for (int i = 0; i < 4; ++i)
        #pragma unroll
        for (int j = 0; j < 4; ++j)
            acc[i][j] = (f32x4){0.f, 0.f, 0.f, 0.f};

    #pragma unroll 1
    for (int ks = 0; ks < 12; ++ks) {
        const int buf = ks & 1;
        __syncthreads();   // waits on staging issued one full phase ago
        if (ks < 11) {
            const int ko = (ks + 1) * 32;
            async16(&As[buf ^ 1][lofs0], ga0 + ko);
            async16(&As[buf ^ 1][lofs1], ga1 + ko);
            async16(&Bs[buf ^ 1][lofs0], gb0 + ko);
            async16(&Bs[buf ^ 1][lofs1], gb1 + ko);
        }

        bf16x8 af[4];
        #pragma unroll
        for (int i = 0; i < 4; ++i)
            af[i] = *(const bf16x8*)(&As[buf][(wm * 64 + i * 16 + col) * 32 + quad * 8]);
        #pragma unroll
        for (int j = 0; j < 4; ++j) {
            bf16x8 bfr = *(const bf16x8*)(&Bs[buf][(wn * 64 + j * 16 + col) * 32 + quad * 8]);
            #pragma unroll
            for (int i = 0; i < 4; ++i)
                acc[i][j] = __builtin_amdgcn_mfma_f32_16x16x32_bf16(
                    af[i], bfr, acc[i][j], 0, 0, 0);
        }
    }

    // epilogue: C/D layout col = lane&15, row = quad*4 + reg
    float mcv[4];
    #pragma unroll
    for (int j = 0; j < 4; ++j) mcv[j] = mc[nb + wn * 64 + j * 16 + col];

    #pragma unroll
    for (int i = 0; i < 4; ++i) {
        float4 xv = *(const float4*)&xcs[wm * 64 + i * 16 + quad * 4];
        float xa[4] = {xv.x, xv.y, xv.z, xv.w};
        #pragma unroll
        for (int r = 0; r < 4; ++r) {
            float s = 0.f;
            #pragma unroll
            for (int j = 0; j < 4; ++j)
                s += __builtin_exp2f(acc[i][j][r] + xa[r] + mcv[j]);
            s += __shfl_xor(s, 1, 16);
            s += __shfl_xor(s, 2, 16);
            s += __shfl_xor(s, 4, 16);
            s += __shfl_xor(s, 8, 16);
            if (col == 0) red[wn][wm * 64 + i * 16 + quad * 4 + r] = s;
        }
    }
    __syncthreads();
    if (tid < 128)
        partials[(size_t)blockIdx.y * MM + m0 + tid] = red[0][tid] + red[1][tid];
}

__global__ __launch_bounds__(256) void gmm_reduce(
    const float* __restrict__ partials, float* __restrict__ out)
{
    int m = blockIdx.x * 256 + threadIdx.x;
    float s = 0.f;
    #pragma unroll 8
    for (int k = 0; k < 64; ++k) s += partials[(size_t)k * MM + m];
    out[m] = COEF * s;
}

// ===========================================================================
// Fallback fp32 path (round-1) — only if ws_size is too small.
// ===========================================================================
__global__ __launch_bounds__(256) void gmm_prep(
    const float* __restrict__ x, const float* __restrict__ means,
    const float* __restrict__ w, float* __restrict__ xc, float* __restrict__ mc)
{
    int tid = blockIdx.x * 256 + threadIdx.x;
    if (tid < MM) {
        const float4* row = (const float4*)(x + (size_t)tid * DD);
        float ss = 0.f;
        #pragma unroll
        for (int i = 0; i < DD / 4; ++i) {
            float4 v = row[i];
            ss = fmaf(v.x, v.x, fmaf(v.y, v.y, fmaf(v.z, v.z, fmaf(v.w, v.w, ss))));
        }
        xc[tid] = -0.5f * ss * L2E;
    } else if (tid < MM + NN) {
        int n = tid - MM;
        const float4* row = (const float4*)(means + (size_t)n * DD);
        float ss = 0.f;
        #pragma unroll
        for (int i = 0; i < DD / 4; ++i) {
            float4 v = row[i];
            ss = fmaf(v.x, v.x, fmaf(v.y, v.y, fmaf(v.z, v.z, fmaf(v.w, v.w, ss))));
        }
        mc[n] = (logf(w[n]) - 0.5f * ss) * L2E;
    }
}

__global__ __launch_bounds__(256, 2) void gmm_main(
    const float* __restrict__ x, const float* __restrict__ means,
    const float* __restrict__ xc, const float* __restrict__ mc,
    float* __restrict__ out)
{
    __shared__ __align__(16) float Asm[128 * 128];
    __shared__ __align__(16) float Bsm[2][16 * 128];

    const int t   = threadIdx.x;
    const int tc  = t & 15;
    const int tr  = t >> 4;
    const int r0  = blockIdx.x * 128;
    const int nq0 = blockIdx.y * 2048;

    {
        float4 tmp[16];
        #pragma unroll
        for (int ii = 0; ii < 16; ++ii) {
            int idx = t + ii * 256;
            int r   = idx >> 5;
            int k0  = (idx & 31) << 2;
            tmp[ii] = *(const float4*)(x + (size_t)(r0 + r) * DD + k0);
        }
        #pragma unroll
        for (int ii = 0; ii < 16; ++ii) {
            int idx = t + ii * 256;
            int r   = idx >> 5;
            int k0  = (idx & 31) << 2;
            int rb  = r >> 3, rl = r & 7;
            float v[4] = {tmp[ii].x, tmp[ii].y, tmp[ii].z, tmp[ii].w};
            #pragma unroll
            for (int j = 0; j < 4; ++j) {
                int k = k0 + j;
                Asm[k * 128 + (((rb ^ (k & 15)) << 3) | rl)] = v[j];
            }
        }
    }

    float xcv[8];
    {
        float4 a = *(const float4*)(xc + r0 + tr * 8);
        float4 b = *(const float4*)(xc + r0 + tr * 8 + 4);
        xcv[0] = a.x; xcv[1] = a.y; xcv[2] = a.z; xcv[3] = a.w;
        xcv[4] = b.x; xcv[5] = b.y; xcv[6] = b.z; xcv[7] = b.w;
    }

    float rowAcc[8];
    #pragma unroll
    for (int i = 0; i < 8; ++i) rowAcc[i] = 0.f;

    for (int ntile = 0; ntile < 16; ++ntile) {
        const int nbase = nq0 + ntile * 128;

        float acc[8][8];
        #pragma unroll
        for (int i = 0; i < 8; ++i)
            #pragma unroll
            for (int j = 0; j < 8; ++j) acc[i][j] = 0.f;

        float4 ld[2];
        #pragma unroll
        for (int ii = 0; ii < 2; ++ii) {
            int flat = t + ii * 256;
            int nl   = flat >> 2;
            int kl   = (flat & 3) << 2;
            ld[ii] = *(const float4*)(means + (size_t)(nbase + nl) * DD + kl);
        }

        for (int ks = 0; ks < 8; ++ks) {
            const int buf = ks & 1;
            #pragma unroll
            for (int ii = 0; ii < 2; ++ii) {
                int flat = t + ii * 256;
                int nl   = flat >> 2;
                int k0   = (flat & 3) << 2;
                int nbk  = nl >> 3, nll = nl & 7;
                float v[4] = {ld[ii].x, ld[ii].y, ld[ii].z, ld[ii].w};
                #pragma unroll
                for (int j = 0; j < 4; ++j) {
                    int kl = k0 + j;
                    Bsm[buf][kl * 128 + (((nbk ^ kl) << 3) | nll)] = v[j];
                }
            }
            if (ks < 7) {
                #pragma unroll
                for (int ii = 0; ii < 2; ++ii) {
                    int flat = t + ii * 256;
                    int nl   = flat >> 2;
                    int kl   = (flat & 3) << 2;
                    ld[ii] = *(const float4*)(means + (size_t)(nbase + nl) * DD
                                              + (ks + 1) * 16 + kl);
                }
            }
            __syncthreads();

            #pragma unroll
            for (int kk = 0; kk < 16; ++kk) {
                const int k = ks * 16 + kk;
                const float* apx = &Asm[k * 128 + ((tr ^ kk) << 3)];
                float4 a0 = *(const float4*)apx;
                float4 a1 = *(const float4*)(apx + 4);
                const float* bpx = &Bsm[buf][kk * 128 + ((tc ^ kk) << 3)];
                float4 b0 = *(const float4*)bpx;
                float4 b1 = *(const float4*)(bpx + 4);
                float av[8] = {a0.x, a0.y, a0.z, a0.w, a1.x, a1.y, a1.z, a1.w};
                float bv[8] = {b0.x, b0.y, b0.z, b0.w, b1.x, b1.y, b1.z, b1.w};
                #pragma unroll
                for (int i = 0; i < 8; ++i)
                    #pragma unroll
                    for (int j = 0; j < 8; ++j)
                        acc[i][j] = fmaf(av[i], bv[j], acc[i][j]);
            }
        }

        float mcv[8];
        {
            float4 a = *(const float4*)(mc + nbase + tc * 8);
            float4 b = *(const float4*)(mc + nbase + tc * 8 + 4);
            mcv[0] = a.x; mcv[1] = a.y; mcv[2] = a.z; mcv[3] = a.w;
            mcv[4] = b.x; mcv[5] = b.y; mcv[6] = b.z; mcv[7] = b.w;
        }
        #pragma unroll
        for (int i = 0; i < 8; ++i) {
            float s = 0.f;
            #pragma unroll
            for (int j = 0; j < 8; ++j) {
                float arg = fmaf(acc[i][j], L2E, xcv[i] + mcv[j]);
                s += __builtin_exp2f(arg);
            }
            rowAcc[i] += s;
        }
    }

    #pragma unroll
    for (int i = 0; i < 8; ++i) {
        float v = rowAcc[i];
        v += __shfl_xor(v, 1, 16);
        v += __shfl_xor(v, 2, 16);
        v += __shfl_xor(v, 4, 16);
        v += __shfl_xor(v, 8, 16);
        if (tc == 0) atomicAdd(out + r0 + tr * 8 + i, COEF * v);
    }
}

extern "C" void kernel_launch(void* const* d_in, const int* in_sizes, int n_in,
                              void* d_out, int out_size, void* d_ws, size_t ws_size,
                              hipStream_t stream) {
    const float* x     = (const float*)d_in[0];
    const float* means = (const float*)d_in[1];
    const float* w     = (const float*)d_in[2];
    float* out = (float*)d_out;

    const size_t needA = (size_t)MM * 384 * sizeof(short);   // 12.6 MB
    const size_t needB = (size_t)NN * 384 * sizeof(short);   //  6.3 MB
    const size_t need  = needA + needB + (size_t)(MM + NN) * 4
                       + (size_t)64 * MM * 4;                // + partials 4 MB

    if (ws_size >= need) {
        short* Acat     = (short*)d_ws;
        short* Bcat     = Acat + (size_t)MM * 384;
        float* xc       = (float*)(Bcat + (size_t)NN * 384);
        float* mc       = xc + MM;
        float* partials = mc + NN;
        gmm_prep_bf16<<<(MM + NN) / 16, 256, 0, stream>>>(x, means, w, Acat, Bcat, xc, mc);
        gmm_mfma<<<dim3(MM / 128, NN / 128), 256, 0, stream>>>(Acat, Bcat, xc, mc, partials);
        gmm_reduce<<<MM / 256, 256, 0, stream>>>(partials, out);
    } else {
        float* xc = (float*)d_ws;
        float* mc = xc + MM;
        hipMemsetAsync(out, 0, MM * sizeof(float), stream);
        gmm_prep<<<(MM + NN + 255) / 256, 256, 0, stream>>>(x, means, w, xc, mc);
        gmm_main<<<dim3(MM / 128, 4), 256, 0, stream>>>(x, means, xc, mc, out);
    }
}

// Round 7
// 209.809 us; speedup vs baseline: 2.3710x; 1.0166x over previous
//
#include <hip/hip_runtime.h>
#include <math.h>

#define MM 16384
#define NN 8192
#define DD 128

#define L2E  1.4426950408889634f
#define COEF 0.15915494309189535f   // 1/(2*pi)

// ---------------------------------------------------------------------------
// bf16 helpers (RNE)
// ---------------------------------------------------------------------------
__device__ __forceinline__ unsigned short f2bf(float f) {
    unsigned u = __float_as_uint(f);
    u = (u + 0x7FFFu + ((u >> 16) & 1u)) >> 16;
    return (unsigned short)u;
}
__device__ __forceinline__ float bf2f(unsigned short h) {
    return __uint_as_float((unsigned)h << 16);
}

__device__ __forceinline__ void async16(short* lds, const short* g) {
    __builtin_amdgcn_global_load_lds(
        (const __attribute__((address_space(1))) unsigned int*)g,
        (__attribute__((address_space(3))) unsigned int*)lds,
        16, 0, 0);
}

typedef __attribute__((ext_vector_type(8))) short bf16x8;
typedef __attribute__((ext_vector_type(4))) float f32x4;

// ---------------------------------------------------------------------------
// Pre-pass with TILED+PERMUTED output layout.
// Acat/Bcat = [rowblock rb (16 rows)][phase ks (0..11)][64 granules of 16B].
// Granule for (row-in-block r', k-granule g) sits at slot r'*4+((g+(r'>>1))&3).
// global_load_lds deposits granule i at LDS slot i, so after DMA the LDS tile
// is already bank-swizzled: frag reads (r'=col, g=quad) hit all 32 banks per
// aligned 8-lane group -> conflict-free ds_read_b128.
// Sections: A phases 0-3=hi(x*L2E), 4-7=lo, 8-11=hi ; B: hi, hi, lo.
// xc[m] = -0.5|x|^2*L2E ; mc[n] = (ln w - 0.5|mu|^2)*L2E
// ---------------------------------------------------------------------------
__global__ __launch_bounds__(256) void gmm_prep_bf16(
    const float* __restrict__ x, const float* __restrict__ means,
    const float* __restrict__ w, short* __restrict__ Acat,
    short* __restrict__ Bcat, float* __restrict__ xc, float* __restrict__ mc)
{
    const int lane = threadIdx.x & 63;
    const int r    = lane >> 4;                 // row within wave's group of 4
    const int c    = lane & 15;                 // 16 lanes per row
    const int row  = (blockIdx.x * 4 + (threadIdx.x >> 6)) * 4 + r;  // 0..24575
    const bool isx = row < MM;
    const int n    = row - MM;

    const float* src = isx ? (x + (size_t)row * DD + c * 8)
                           : (means + (size_t)n * DD + c * 8);
    float4 v0 = ((const float4*)src)[0];
    float4 v1 = ((const float4*)src)[1];
    float a[8] = {v0.x, v0.y, v0.z, v0.w, v1.x, v1.y, v1.z, v1.w};

    float ss = 0.f;
    #pragma unroll
    for (int k = 0; k < 8; ++k) ss = fmaf(a[k], a[k], ss);

    if (isx) {
        #pragma unroll
        for (int k = 0; k < 8; ++k) a[k] *= L2E;
    }

    unsigned hi[4], lo[4];
    #pragma unroll
    for (int k = 0; k < 4; ++k) {
        unsigned short h0 = f2bf(a[2 * k]),     h1 = f2bf(a[2 * k + 1]);
        unsigned short l0 = f2bf(a[2 * k] - bf2f(h0));
        unsigned short l1 = f2bf(a[2 * k + 1] - bf2f(h1));
        hi[k] = (unsigned)h0 | ((unsigned)h1 << 16);
        lo[k] = (unsigned)l0 | ((unsigned)l1 << 16);
    }
    uint4 HI = make_uint4(hi[0], hi[1], hi[2], hi[3]);
    uint4 LO = make_uint4(lo[0], lo[1], lo[2], lo[3]);

    // tiled/permuted destination
    const int rr   = isx ? row : n;
    const int rb   = rr >> 4, rp = rr & 15;
    const int g    = c & 3,   ph = c >> 2;                 // k-granule, phase
    const int slot = rp * 4 + ((g + (rp >> 1)) & 3);       // bank swizzle
    short* base = (isx ? Acat : Bcat) + (size_t)rb * 6144 + slot * 8;
    *(uint4*)(base + ph * 512)       = HI;                 // phases 0..3
    *(uint4*)(base + (ph + 4) * 512) = isx ? LO : HI;      // phases 4..7
    *(uint4*)(base + (ph + 8) * 512) = isx ? HI : LO;      // phases 8..11

    ss += __shfl_xor(ss, 1, 16);
    ss += __shfl_xor(ss, 2, 16);
    ss += __shfl_xor(ss, 4, 16);
    ss += __shfl_xor(ss, 8, 16);
    if (c == 0) {
        if (isx) xc[row] = -0.5f * ss * L2E;
        else     mc[n]   = (logf(w[n]) - 0.5f * ss) * L2E;
    }
}

// ---------------------------------------------------------------------------
// Main MFMA kernel — round-5 proven skeleton ((256,3), dbuf staging, prefetch
// issued AFTER the barrier, one barrier per k-step) + bank-conflict-free LDS:
// the global layout is pre-permuted so the lane-i->slot-i DMA yields swizzled
// tiles; frag reads add ((quad+(col>>1))&3)*8 and hit all 32 banks per beat.
// Staging global reads are fully contiguous (1KB per global_load_lds).
// 128x128 tile, 4 waves 2x2, 12 phases of BK=32 (3-pass hi/lo bf16 split).
// Epilogue: exp2(acc + xc + mc), width-16 shuffle reduce, partials store.
// ---------------------------------------------------------------------------
__global__ __launch_bounds__(256, 3) void gmm_mfma(
    const short* __restrict__ Acat, const short* __restrict__ Bcat,
    const float* __restrict__ xc, const float* __restrict__ mc,
    float* __restrict__ partials)
{
    __shared__ __align__(16) short As[2][4096];   // 2 x 8 KB, 8 tiles x 512
    __shared__ __align__(16) short Bs[2][4096];   // 2 x 8 KB
    __shared__ __align__(16) float xcs[128];
    __shared__ float red[2][128];

    const int tid  = threadIdx.x;
    const int w    = tid >> 6, lane = tid & 63;
    const int wm   = w >> 1,   wn   = w & 1;
    const int quad = lane >> 4, col = lane & 15;
    const int m0   = blockIdx.x * 128;
    const int nb   = blockIdx.y * 128;

    // wave w stages row-blocks {w*2, w*2+1} of both A and B (contiguous 1KB)
    const short* ga0 = Acat + (size_t)(blockIdx.x * 8 + w * 2) * 6144 + lane * 8;
    const short* ga1 = ga0 + 6144;
    const short* gb0 = Bcat + (size_t)(blockIdx.y * 8 + w * 2) * 6144 + lane * 8;
    const short* gb1 = gb0 + 6144;
    const int lofs0 = w * 1024;        // tile (w*2)   * 512 shorts
    const int lofs1 = w * 1024 + 512;  // tile (w*2+1) * 512 shorts

    if (tid < 128) xcs[tid] = xc[m0 + tid];

    // stage phase 0 into buffer 0
    async16(&As[0][lofs0], ga0);
    async16(&As[0][lofs1], ga1);
    async16(&Bs[0][lofs0], gb0);
    async16(&Bs[0][lofs1], gb1);

    f32x4 acc[4][4];
    #pragma unroll
    for (int i = 0; i < 4; ++i)
        #pragma unroll
        for (int j = 0; j < 4; ++j)
            acc[i][j] = (f32x4){0.f, 0.f, 0.f, 0.f};

    // swizzled in-tile read offset (shorts): r'=col, g=quad
    const int rdo = col * 32 + ((quad + (col >> 1)) & 3) * 8;

    #pragma unroll 1
    for (int ks = 0; ks < 12; ++ks) {
        const int buf = ks & 1;
        __syncthreads();   // waits on staging issued one full phase ago
        if (ks < 11) {
            const int ko = (ks + 1) * 512;
            async16(&As[buf ^ 1][lofs0], ga0 + ko);
            async16(&As[buf ^ 1][lofs1], ga1 + ko);
            async16(&Bs[buf ^ 1][lofs0], gb0 + ko);
            async16(&Bs[buf ^ 1][lofs1], gb1 + ko);
        }

        bf16x8 af[4];
        #pragma unroll
        for (int i = 0; i < 4; ++i)
            af[i] = *(const bf16x8*)(&As[buf][(wm * 4 + i) * 512 + rdo]);
        #pragma unroll
        for (int j = 0; j < 4; ++j) {
            bf16x8 bfr = *(const bf16x8*)(&Bs[buf][(wn * 4 + j) * 512 + rdo]);
            #pragma unroll
            for (int i = 0; i < 4; ++i)
                acc[i][j] = __builtin_amdgcn_mfma_f32_16x16x32_bf16(
                    af[i], bfr, acc[i][j], 0, 0, 0);
        }
    }

    // epilogue: C/D layout col = lane&15, row = quad*4 + reg
    float mcv[4];
    #pragma unroll
    for (int j = 0; j < 4; ++j) mcv[j] = mc[nb + wn * 64 + j * 16 + col];

    #pragma unroll
    for (int i = 0; i < 4; ++i) {
        float4 xv = *(const float4*)&xcs[wm * 64 + i * 16 + quad * 4];
        float xa[4] = {xv.x, xv.y, xv.z, xv.w};
        #pragma unroll
        for (int r = 0; r < 4; ++r) {
            float s = 0.f;
            #pragma unroll
            for (int j = 0; j < 4; ++j)
                s += __builtin_exp2f(acc[i][j][r] + xa[r] + mcv[j]);
            s += __shfl_xor(s, 1, 16);
            s += __shfl_xor(s, 2, 16);
            s += __shfl_xor(s, 4, 16);
            s += __shfl_xor(s, 8, 16);
            if (col == 0) red[wn][wm * 64 + i * 16 + quad * 4 + r] = s;
        }
    }
    __syncthreads();
    if (tid < 128)
        partials[(size_t)blockIdx.y * MM + m0 + tid] = red[0][tid] + red[1][tid];
}

__global__ __launch_bounds__(256) void gmm_reduce(
    const float* __restrict__ partials, float* __restrict__ out)
{
    int m = blockIdx.x * 256 + threadIdx.x;
    float s = 0.f;
    #pragma unroll 8
    for (int k = 0; k < 64; ++k) s += partials[(size_t)k * MM + m];
    out[m] = COEF * s;
}

// ===========================================================================
// Fallback fp32 path (round-1) — only if ws_size is too small.
// ===========================================================================
__global__ __launch_bounds__(256) void gmm_prep(
    const float* __restrict__ x, const float* __restrict__ means,
    const float* __restrict__ w, float* __restrict__ xc, float* __restrict__ mc)
{
    int tid = blockIdx.x * 256 + threadIdx.x;
    if (tid < MM) {
        const float4* row = (const float4*)(x + (size_t)tid * DD);
        float ss = 0.f;
        #pragma unroll
        for (int i = 0; i < DD / 4; ++i) {
            float4 v = row[i];
            ss = fmaf(v.x, v.x, fmaf(v.y, v.y, fmaf(v.z, v.z, fmaf(v.w, v.w, ss))));
        }
        xc[tid] = -0.5f * ss * L2E;
    } else if (tid < MM + NN) {
        int n = tid - MM;
        const float4* row = (const float4*)(means + (size_t)n * DD);
        float ss = 0.f;
        #pragma unroll
        for (int i = 0; i < DD / 4; ++i) {
            float4 v = row[i];
            ss = fmaf(v.x, v.x, fmaf(v.y, v.y, fmaf(v.z, v.z, fmaf(v.w, v.w, ss))));
        }
        mc[n] = (logf(w[n]) - 0.5f * ss) * L2E;
    }
}

__global__ __launch_bounds__(256, 2) void gmm_main(
    const float* __restrict__ x, const float* __restrict__ means,
    const float* __restrict__ xc, const float* __restrict__ mc,
    float* __restrict__ out)
{
    __shared__ __align__(16) float Asm[128 * 128];
    __shared__ __align__(16) float Bsm[2][16 * 128];

    const int t   = threadIdx.x;
    const int tc  = t & 15;
    const int tr  = t >> 4;
    const int r0  = blockIdx.x * 128;
    const int nq0 = blockIdx.y * 2048;

    {
        float4 tmp[16];
        #pragma unroll
        for (int ii = 0; ii < 16; ++ii) {
            int idx = t + ii * 256;
            int r   = idx >> 5;
            int k0  = (idx & 31) << 2;
            tmp[ii] = *(const float4*)(x + (size_t)(r0 + r) * DD + k0);
        }
        #pragma unroll
        for (int ii = 0; ii < 16; ++ii) {
            int idx = t + ii * 256;
            int r   = idx >> 5;
            int k0  = (idx & 31) << 2;
            int rb  = r >> 3, rl = r & 7;
            float v[4] = {tmp[ii].x, tmp[ii].y, tmp[ii].z, tmp[ii].w};
            #pragma unroll
            for (int j = 0; j < 4; ++j) {
                int k = k0 + j;
                Asm[k * 128 + (((rb ^ (k & 15)) << 3) | rl)] = v[j];
            }
        }
    }

    float xcv[8];
    {
        float4 a = *(const float4*)(xc + r0 + tr * 8);
        float4 b = *(const float4*)(xc + r0 + tr * 8 + 4);
        xcv[0] = a.x; xcv[1] = a.y; xcv[2] = a.z; xcv[3] = a.w;
        xcv[4] = b.x; xcv[5] = b.y; xcv[6] = b.z; xcv[7] = b.w;
    }

    float rowAcc[8];
    #pragma unroll
    for (int i = 0; i < 8; ++i) rowAcc[i] = 0.f;

    for (int ntile = 0; ntile < 16; ++ntile) {
        const int nbase = nq0 + ntile * 128;

        float acc[8][8];
        #pragma unroll
        for (int i = 0; i < 8; ++i)
            #pragma unroll
            for (int j = 0; j < 8; ++j) acc[i][j] = 0.f;

        float4 ld[2];
        #pragma unroll
        for (int ii = 0; ii < 2; ++ii) {
            int flat = t + ii * 256;
            int nl   = flat >> 2;
            int kl   = (flat & 3) << 2;
            ld[ii] = *(const float4*)(means + (size_t)(nbase + nl) * DD + kl);
        }

        for (int ks = 0; ks < 8; ++ks) {
            const int buf = ks & 1;
            #pragma unroll
            for (int ii = 0; ii < 2; ++ii) {
                int flat = t + ii * 256;
                int nl   = flat >> 2;
                int k0   = (flat & 3) << 2;
                int nbk  = nl >> 3, nll = nl & 7;
                float v[4] = {ld[ii].x, ld[ii].y, ld[ii].z, ld[ii].w};
                #pragma unroll
                for (int j = 0; j < 4; ++j) {
                    int kl = k0 + j;
                    Bsm[buf][kl * 128 + (((nbk ^ kl) << 3) | nll)] = v[j];
                }
            }
            if (ks < 7) {
                #pragma unroll
                for (int ii = 0; ii < 2; ++ii) {
                    int flat = t + ii * 256;
                    int nl   = flat >> 2;
                    int kl   = (flat & 3) << 2;
                    ld[ii] = *(const float4*)(means + (size_t)(nbase + nl) * DD
                                              + (ks + 1) * 16 + kl);
                }
            }
            __syncthreads();

            #pragma unroll
            for (int kk = 0; kk < 16; ++kk) {
                const int k = ks * 16 + kk;
                const float* apx = &Asm[k * 128 + ((tr ^ kk) << 3)];
                float4 a0 = *(const float4*)apx;
                float4 a1 = *(const float4*)(apx + 4);
                const float* bpx = &Bsm[buf][kk * 128 + ((tc ^ kk) << 3)];
                float4 b0 = *(const float4*)bpx;
                float4 b1 = *(const float4*)(bpx + 4);
                float av[8] = {a0.x, a0.y, a0.z, a0.w, a1.x, a1.y, a1.z, a1.w};
                float bv[8] = {b0.x, b0.y, b0.z, b0.w, b1.x, b1.y, b1.z, b1.w};
                #pragma unroll
                for (int i = 0; i < 8; ++i)
                    #pragma unroll
                    for (int j = 0; j < 8; ++j)
                        acc[i][j] = fmaf(av[i], bv[j], acc[i][j]);
            }
        }

        float mcv[8];
        {
            float4 a = *(const float4*)(mc + nbase + tc * 8);
            float4 b = *(const float4*)(mc + nbase + tc * 8 + 4);
            mcv[0] = a.x; mcv[1] = a.y; mcv[2] = a.z; mcv[3] = a.w;
            mcv[4] = b.x; mcv[5] = b.y; mcv[6] = b.z; mcv[7] = b.w;
        }
        #pragma unroll
        for (int i = 0; i < 8; ++i) {
            float s = 0.f;
            #pragma unroll
            for (int j = 0; j < 8; ++j) {
                float arg = fmaf(acc[i][j], L2E, xcv[i] + mcv[j]);
                s += __builtin_exp2f(arg);
            }
            rowAcc[i] += s;
        }
    }

    #pragma unroll
    for (int i = 0; i < 8; ++i) {
        float v = rowAcc[i];
        v += __shfl_xor(v, 1, 16);
        v += __shfl_xor(v, 2, 16);
        v += __shfl_xor(v, 4, 16);
        v += __shfl_xor(v, 8, 16);
        if (tc == 0) atomicAdd(out + r0 + tr * 8 + i, COEF * v);
    }
}

extern "C" void kernel_launch(void* const* d_in, const int* in_sizes, int n_in,
                              void* d_out, int out_size, void* d_ws, size_t ws_size,
                              hipStream_t stream) {
    const float* x     = (const float*)d_in[0];
    const float* means = (const float*)d_in[1];
    const float* w     = (const float*)d_in[2];
    float* out = (float*)d_out;

    const size_t needA = (size_t)MM * 384 * sizeof(short);   // 12.6 MB
    const size_t needB = (size_t)NN * 384 * sizeof(short);   //  6.3 MB
    const size_t need  = needA + needB + (size_t)(MM + NN) * 4
                       + (size_t)64 * MM * 4;                // + partials 4 MB

    if (ws_size >= need) {
        short* Acat     = (short*)d_ws;
        short* Bcat     = Acat + (size_t)MM * 384;
        float* xc       = (float*)(Bcat + (size_t)NN * 384);
        float* mc       = xc + MM;
        float* partials = mc + NN;
        gmm_prep_bf16<<<(MM + NN) / 16, 256, 0, stream>>>(x, means, w, Acat, Bcat, xc, mc);
        gmm_mfma<<<dim3(MM / 128, NN / 128), 256, 0, stream>>>(Acat, Bcat, xc, mc, partials);
        gmm_reduce<<<MM / 256, 256, 0, stream>>>(partials, out);
    } else {
        float* xc = (float*)d_ws;
        float* mc = xc + MM;
        hipMemsetAsync(out, 0, MM * sizeof(float), stream);
        gmm_prep<<<(MM + NN + 255) / 256, 256, 0, stream>>>(x, means, w, xc, mc);
        gmm_main<<<dim3(MM / 128, 4), 256, 0, stream>>>(x, means, xc, mc, out);
    }
}